// Round 6
// baseline (299.755 us; speedup 1.0000x reference)
//
#include <hip/hip_runtime.h>

using bf16x8 = __attribute__((ext_vector_type(8))) short;
using f32x4  = __attribute__((ext_vector_type(4))) float;

#define NB 64
#define CLN 1024
#define QLN 128
#define DDN 512

typedef __attribute__((address_space(1))) const void GAS;
typedef __attribute__((address_space(3))) void LAS;

__device__ __forceinline__ unsigned f2bf(float x){
    union { float f; unsigned u; } v; v.f = x;
    unsigned r = v.u + 0x7FFFu + ((v.u >> 16) & 1u);   // RNE
    return r >> 16;
}
__device__ __forceinline__ float bf2f(unsigned short u){
    union { unsigned u; float f; } v; v.u = ((unsigned)u) << 16; return v.f;
}

// ---------------- K0: qT[b][d][j] = bf16(q[b][j][d]); qbf[b][j][d] ----------------
__global__ __launch_bounds__(256) void k0_qprep(const float* __restrict__ q,
        unsigned short* __restrict__ qT, unsigned short* __restrict__ qbf){
    __shared__ float tile[QLN][65];
    const int b  = blockIdx.x;
    const int d0 = blockIdx.y * 64;
    const int t  = threadIdx.x;
    {
        const int col = t & 63, rg = t >> 6;
        #pragma unroll 4
        for (int p = 0; p < 32; ++p){
            int j = p*4 + rg;
            float v = q[(size_t)(b*QLN + j)*DDN + d0 + col];
            tile[j][col] = v;
            qbf[(size_t)(b*QLN + j)*DDN + d0 + col] = (unsigned short)f2bf(v);
        }
    }
    __syncthreads();
    {
        const int j = t & 127, dg = t >> 7;
        #pragma unroll 4
        for (int p = 0; p < 32; ++p){
            int dd = p*2 + dg;
            qT[(size_t)(b*DDN + d0 + dd)*QLN + j] = (unsigned short)f2bf(tile[j][dd]);
        }
    }
}

// ---------------- K0b: s_q[b][j] = q[b][j][:] . w_q ----------------
__global__ __launch_bounds__(256) void k0b_sq(const float* __restrict__ q,
        const float* __restrict__ w_q, float* __restrict__ sq){
    const int b = blockIdx.x;
    const int t = threadIdx.x;
    const int wave = t >> 6, lane = t & 63;
    float wv[8];
    #pragma unroll
    for (int e=0;e<8;++e) wv[e] = w_q[lane*8+e];
    for (int j = wave; j < QLN; j += 4){
        const float* qr = q + (size_t)(b*QLN + j)*DDN + lane*8;
        float s = 0.f;
        #pragma unroll
        for (int e=0;e<8;++e) s += qr[e]*wv[e];
        #pragma unroll
        for (int m=1;m<64;m<<=1) s += __shfl_xor(s, m, 64);
        if (lane==0) sq[b*QLN + j] = s;
    }
}

// ---------------- K0c: q0 = c (exact, nt); cbf = bf16(c*w_cq) into out-q3 slack;
//                       s_c = c . w_c; block 0 also writes inv_wcq ----------------
__global__ __launch_bounds__(256) void k0c_cprep(const float* __restrict__ c,
        const float* __restrict__ w_c, const float* __restrict__ w_cq,
        float* out, float* __restrict__ sc_ws, float* __restrict__ inv_ws){
    const int t = threadIdx.x, lane = t & 63, w = t >> 6;
    const int row0 = blockIdx.x*32 + w*8;
    float4 wc0 = *(const float4*)(w_c  + lane*8);
    float4 wc1 = *(const float4*)(w_c  + lane*8 + 4);
    float4 wq0 = *(const float4*)(w_cq + lane*8);
    float4 wq1 = *(const float4*)(w_cq + lane*8 + 4);
    #pragma unroll 2
    for (int p=0;p<8;++p){
        const size_t gi = (size_t)(row0 + p);
        const float* cr = c + gi*DDN + lane*8;
        f32x4 a  = *(const f32x4*)cr;
        f32x4 bb = *(const f32x4*)(cr+4);
        float s = a.x*wc0.x + a.y*wc0.y + a.z*wc0.z + a.w*wc0.w
                + bb.x*wc1.x + bb.y*wc1.y + bb.z*wc1.z + bb.w*wc1.w;
        #pragma unroll
        for (int m=1;m<64;m<<=1) s += __shfl_xor(s, m, 64);
        float* orow = out + gi*2048;
        __builtin_nontemporal_store(a,  (f32x4*)(orow + lane*8));
        __builtin_nontemporal_store(bb, (f32x4*)(orow + lane*8 + 4));
        uint4 pk;
        pk.x = f2bf(a.x*wq0.x)  | (f2bf(a.y*wq0.y)  << 16);
        pk.y = f2bf(a.z*wq0.z)  | (f2bf(a.w*wq0.w)  << 16);
        pk.z = f2bf(bb.x*wq1.x) | (f2bf(bb.y*wq1.y) << 16);
        pk.w = f2bf(bb.z*wq1.z) | (f2bf(bb.w*wq1.w) << 16);
        *(uint4*)((unsigned short*)(orow + 1792) + lane*8) = pk;   // cbf (cacheable)
        if (lane==0) sc_ws[gi] = s;
    }
    if (blockIdx.x == 0){
        for (int d=t; d<DDN; d+=256){
            float wv = w_cq[d];
            inv_ws[d] = (fabsf(wv) > 1e-35f) ? 1.0f/wv : 0.0f;
        }
    }
}

// staging: one wave fills 2 chunks of 8 rows (128B/row, XOR-swizzled source)
__device__ __forceinline__ void stage64(const float* out, size_t girow0, int kc,
        unsigned short* buf, int wm, int lane){
    const int rsub = lane >> 3, c16 = lane & 7;
    #pragma unroll
    for (int r=0;r<2;++r){
        const int chunk = wm*2 + r;
        const int row   = chunk*8 + rsub;
        const int col16 = c16 ^ (row & 7);
        const unsigned short* g =
            (const unsigned short*)(out + (girow0 + row)*2048 + 1792) + kc*64 + col16*8;
        __builtin_amdgcn_global_load_lds((GAS*)g, (LAS*)(buf + chunk*512), 16, 0, 0);
    }
}

// ---------------- K1: 64-row tiles, 1024 blocks (4/CU).
//   GEMM1^T (D[j][i]) -> softmax -> GEMM2^T (D[d][i]) -> float4 epilogue ----------------
__global__ __launch_bounds__(256,4) void k1_main(
        float* out, const unsigned short* __restrict__ qbf,
        const unsigned short* __restrict__ qT, const float* __restrict__ sq_ws,
        const float* __restrict__ sc_ws, const float* __restrict__ inv_ws,
        float* __restrict__ vts, float* __restrict__ Mts, float* __restrict__ Sts){
    __shared__ unsigned short sm_u[8192];    // 16KB: staging dbuf (2x8KB) / P^T alias (64x256B)
    __shared__ float sm_vw[4][512];          // 8KB per-wave v_t slabs
    __shared__ float sm_inv[512];            // 2KB
    __shared__ float sm_sq[128], sm_m[64], sm_sc[64];

    const int bid  = blockIdx.x;
    const int swzb = (bid & 7)*128 + (bid >> 3);   // batch's 16 slabs share an XCD
    const int b    = swzb >> 4;
    const int slab = swzb & 15;
    const int i0   = slab * 64;
    const int t    = threadIdx.x;
    const int lane = t & 63;
    const int wm   = t >> 6;
    const int l15  = lane & 15;
    const int l4   = lane >> 4;
    const size_t girow0 = (size_t)(b*CLN + i0);

    if (t < 64) sm_sc[t] = sc_ws[girow0 + t];
    if (t >= 128 && t < 256) sm_sq[t-128] = sq_ws[b*QLN + (t-128)];
    sm_inv[t] = inv_ws[t]; sm_inv[t+256] = inv_ws[t+256];

    f32x4 acc[8];
    #pragma unroll
    for (int nj=0;nj<8;++nj) acc[nj] = f32x4{0.f,0.f,0.f,0.f};

    // ---- GEMM1: D[j][i] = sum_d qbf[j][d] * cbf[i][d] ----
    stage64(out, girow0, 0, sm_u, wm, lane);
    __syncthreads();
    const unsigned short* qbbase = qbf + (size_t)b*QLN*DDN;
    const int arow = wm*16 + l15;
    for (int kc=0; kc<8; ++kc){
        const int cur = kc & 1;
        if (kc < 7) stage64(out, girow0, kc+1, sm_u + (cur^1)*4096, wm, lane);
        const char* abase = (const char*)(sm_u + cur*4096);
        #pragma unroll
        for (int ks=0; ks<2; ++ks){
            bf16x8 af = *(const bf16x8*)(abase + arow*128 + ((ks*64 + l4*16) ^ ((arow&7)<<4)));
            bf16x8 bfr[8];
            #pragma unroll
            for (int nj=0;nj<8;++nj)
                bfr[nj] = *(const bf16x8*)(qbbase + (size_t)(nj*16+l15)*DDN + kc*64 + ks*32 + l4*8);
            #pragma unroll
            for (int nj=0;nj<8;++nj)
                acc[nj] = __builtin_amdgcn_mfma_f32_16x16x32_bf16(bfr[nj], af, acc[nj], 0,0,0);
        }
        __syncthreads();
    }

    // ---- row softmax: lane owns row i = wm*16+l15; j = nj*16 + l4*4 + r ----
    const int irow = arow;
    f32x4 sq4[8];
    #pragma unroll
    for (int nj=0;nj<8;++nj) sq4[nj] = *(const f32x4*)(sm_sq + nj*16 + l4*4);

    float rmax = -1e30f;
    #pragma unroll
    for (int nj=0;nj<8;++nj){
        #pragma unroll
        for (int r=0;r<4;++r){
            float v = acc[nj][r] + sq4[nj][r];
            acc[nj][r] = v;
            rmax = fmaxf(rmax, v);
        }
    }
    rmax = fmaxf(rmax, __shfl_xor(rmax, 16, 64));
    rmax = fmaxf(rmax, __shfl_xor(rmax, 32, 64));
    if (l4 == 0) sm_m[irow] = sm_sc[irow] + rmax;
    float rsum = 0.f;
    #pragma unroll
    for (int nj=0;nj<8;++nj){
        #pragma unroll
        for (int r=0;r<4;++r){
            float pv = __expf(acc[nj][r] - rmax);
            acc[nj][r] = pv;
            rsum += pv;
        }
    }
    rsum += __shfl_xor(rsum, 16, 64);
    rsum += __shfl_xor(rsum, 32, 64);
    const float pinv = 1.f / rsum;
    #pragma unroll
    for (int nj=0;nj<8;++nj){
        uint2 u;
        u.x = f2bf(acc[nj][0]*pinv) | (f2bf(acc[nj][1]*pinv) << 16);
        u.y = f2bf(acc[nj][2]*pinv) | (f2bf(acc[nj][3]*pinv) << 16);
        *(uint2*)((char*)sm_u + irow*256 + ((nj*32 + l4*8) ^ ((irow&7)<<4))) = u;
    }
    __syncthreads();   // P^T + sm_m visible

    // ---- slab max/sum for b_att (each wave redundantly reduces the 64 values) ----
    float mv = sm_m[lane];
    #pragma unroll
    for (int m=1;m<64;m<<=1) mv = fmaxf(mv, __shfl_xor(mv, m, 64));
    const float mt = mv;
    float es = __expf(sm_m[lane] - mt);
    #pragma unroll
    for (int m=1;m<64;m<<=1) es += __shfl_xor(es, m, 64);
    const float wrow = __expf(sm_m[irow] - mt);
    if (t == 0){ Mts[b*16 + slab] = mt; Sts[b*16 + slab] = es; }

    // ---- GEMM2: D[d][i] = sum_j qT[d][j] * P^T[i][j]; float4 epilogue ----
    const unsigned short* qtbase = qT + (size_t)b*DDN*QLN;
    for (int dc=0; dc<4; ++dc){
        f32x4 acc2[8];
        #pragma unroll
        for (int dt=0;dt<8;++dt) acc2[dt] = f32x4{0.f,0.f,0.f,0.f};
        #pragma unroll
        for (int jc=0; jc<4; ++jc){
            bf16x8 b2 = *(const bf16x8*)((char*)sm_u + irow*256 + ((jc*64 + l4*16) ^ ((irow&7)<<4)));
            #pragma unroll
            for (int dt=0;dt<8;++dt){
                bf16x8 a2 = *(const bf16x8*)(qtbase + (size_t)(dc*128 + dt*16 + l15)*QLN + jc*32 + l4*8);
                acc2[dt] = __builtin_amdgcn_mfma_f32_16x16x32_bf16(a2, b2, acc2[dt], 0,0,0);
            }
        }
        #pragma unroll
        for (int dt=0; dt<8; ++dt){
            const int d0 = dc*128 + dt*16 + l4*4;
            f32x4 iv = *(const f32x4*)(sm_inv + d0);
            const size_t gi = girow0 + irow;
            const unsigned short* cb = (const unsigned short*)(out + gi*2048 + 1792) + d0;
            uint2 u = *(const uint2*)cb;   // 4 bf16, L2-hot
            f32x4 cv;
            cv.x = bf2f((unsigned short)(u.x & 0xffff)) * iv.x;
            cv.y = bf2f((unsigned short)(u.x >> 16))    * iv.y;
            cv.z = bf2f((unsigned short)(u.y & 0xffff)) * iv.z;
            cv.w = bf2f((unsigned short)(u.y >> 16))    * iv.w;
            f32x4 v = acc2[dt];
            float* orow = out + gi*2048;
            __builtin_nontemporal_store(v,  (f32x4*)(orow + 512 + d0));     // q1 = c2q
            f32x4 cq; cq.x=cv.x*v.x; cq.y=cv.y*v.y; cq.z=cv.z*v.z; cq.w=cv.w*v.w;
            __builtin_nontemporal_store(cq, (f32x4*)(orow + 1024 + d0));    // q2 = c*c2q
            f32x4 vp;
            vp.x = wrow*cv.x; vp.y = wrow*cv.y; vp.z = wrow*cv.z; vp.w = wrow*cv.w;
            #pragma unroll
            for (int m=1;m<16;m<<=1){
                vp.x += __shfl_xor(vp.x, m, 64); vp.y += __shfl_xor(vp.y, m, 64);
                vp.z += __shfl_xor(vp.z, m, 64); vp.w += __shfl_xor(vp.w, m, 64);
            }
            if (l15 == 0) *(f32x4*)(&sm_vw[wm][d0]) = vp;
        }
    }
    __syncthreads();
    for (int d=t; d<DDN; d+=256){
        float s = sm_vw[0][d] + sm_vw[1][d] + sm_vw[2][d] + sm_vw[3][d];
        vts[(size_t)(b*16 + slab)*DDN + d] = s;
    }
}

// ---------------- K2: combine 16 slabs -> q2c[b][d] ----------------
__global__ __launch_bounds__(256) void k2_combine(const float* __restrict__ vts,
        const float* __restrict__ Mts, const float* __restrict__ Sts,
        float* __restrict__ q2c){
    const int b = blockIdx.x, t = threadIdx.x;
    float Mt[16]; float M = -1e30f;
    #pragma unroll
    for (int i=0;i<16;++i){ Mt[i] = Mts[b*16+i]; M = fmaxf(M, Mt[i]); }
    float coef[16]; float denom = 0.f;
    #pragma unroll
    for (int i=0;i<16;++i){ coef[i] = __expf(Mt[i]-M); denom += coef[i]*Sts[b*16+i]; }
    const float inv = 1.f/denom;
    for (int d=t; d<DDN; d+=256){
        float s = 0.f;
        #pragma unroll
        for (int i=0;i<16;++i) s += coef[i]*vts[(size_t)(b*16+i)*DDN + d];
        q2c[b*DDN + d] = s*inv;
    }
}

// ---------------- K3: q3 = c * q2c (c reconstructed from cbf slack) ----------------
__global__ __launch_bounds__(256) void k3_cq2c(float* out,
        const float* __restrict__ q2c, const float* __restrict__ inv_ws){
    const int t = threadIdx.x;
    const int rloc = t >> 6, ch = t & 63;
    for (int pass=0; pass<8; ++pass){
        const size_t rb = (size_t)blockIdx.x + (size_t)pass*2048;
        const size_t gi = rb*4 + rloc;
        const int b = (int)(gi >> 10);
        const unsigned short* cb = (const unsigned short*)(out + gi*2048 + 1792) + ch*8;
        uint4 raw = *(const uint4*)cb;
        const float* qp = q2c + b*DDN + ch*8;
        float4 qa = *(const float4*)qp;
        float4 qb = *(const float4*)(qp+4);
        const float* ip = inv_ws + ch*8;
        float4 ia = *(const float4*)ip;
        float4 ib = *(const float4*)(ip+4);
        f32x4 o0, o1;
        o0.x = bf2f((unsigned short)(raw.x & 0xffff)) * ia.x * qa.x;
        o0.y = bf2f((unsigned short)(raw.x >> 16))    * ia.y * qa.y;
        o0.z = bf2f((unsigned short)(raw.y & 0xffff)) * ia.z * qa.z;
        o0.w = bf2f((unsigned short)(raw.y >> 16))    * ia.w * qa.w;
        o1.x = bf2f((unsigned short)(raw.z & 0xffff)) * ib.x * qb.x;
        o1.y = bf2f((unsigned short)(raw.z >> 16))    * ib.y * qb.y;
        o1.z = bf2f((unsigned short)(raw.w & 0xffff)) * ib.z * qb.z;
        o1.w = bf2f((unsigned short)(raw.w >> 16))    * ib.w * qb.w;
        __syncthreads();   // all 4 rows' cbf read before any q3 overwrite
        f32x4* wp = (f32x4*)(out + gi*2048 + 1536) + ch*2;
        __builtin_nontemporal_store(o0, wp);
        __builtin_nontemporal_store(o1, wp+1);
    }
}

extern "C" void kernel_launch(void* const* d_in, const int* in_sizes, int n_in,
                              void* d_out, int out_size, void* d_ws, size_t ws_size,
                              hipStream_t stream) {
    const float* c    = (const float*)d_in[0];
    const float* q    = (const float*)d_in[1];
    const float* w_c  = (const float*)d_in[2];
    const float* w_q  = (const float*)d_in[4];
    const float* w_cq = (const float*)d_in[6];
    float* out = (float*)d_out;

    char* ws = (char*)d_ws;
    unsigned short* qT  = (unsigned short*)ws;                     // 8 MiB
    unsigned short* qbf = (unsigned short*)(ws + 8388608);         // 8 MiB
    float* sq  = (float*)(ws + 16777216);                          // 32 KB
    float* sc  = (float*)(ws + 16777216 + 32768);                  // 256 KB
    float* inv = (float*)(ws + 16777216 + 32768 + 262144);         // 2 KB
    float* Mts = (float*)(ws + 16777216 + 32768 + 262144 + 2048);  // 4 KB
    float* Sts = (float*)(ws + 16777216 + 32768 + 262144 + 6144);  // 4 KB
    float* vts = (float*)(ws + 16777216 + 32768 + 262144 + 10240); // 2 MiB
    float* q2c = (float*)(ws + 16777216 + 32768 + 262144 + 10240 + 2097152); // 128 KB

    k0_qprep<<<dim3(NB, 8), 256, 0, stream>>>(q, qT, qbf);
    k0b_sq<<<NB, 256, 0, stream>>>(q, w_q, sq);
    k0c_cprep<<<2048, 256, 0, stream>>>(c, w_c, w_cq, out, sc, inv);
    k1_main<<<1024, 256, 0, stream>>>(out, qbf, qT, sq, sc, inv, vts, Mts, Sts);
    k2_combine<<<NB, 256, 0, stream>>>(vts, Mts, Sts, q2c);
    k3_cq2c<<<2048, 256, 0, stream>>>(out, q2c, inv);
}

// Round 8
// 280.064 us; speedup vs baseline: 1.0703x; 1.0703x over previous
//
#include <hip/hip_runtime.h>

using bf16x8 = __attribute__((ext_vector_type(8))) short;
using f32x4  = __attribute__((ext_vector_type(4))) float;

#define NB 64
#define CLN 1024
#define QLN 128
#define DDN 512

typedef __attribute__((address_space(1))) const void GAS;
typedef __attribute__((address_space(3))) void LAS;

__device__ __forceinline__ unsigned f2bf(float x){
    union { float f; unsigned u; } v; v.f = x;
    unsigned r = v.u + 0x7FFFu + ((v.u >> 16) & 1u);   // RNE
    return r >> 16;
}
__device__ __forceinline__ float bf2f(unsigned short u){
    union { unsigned u; float f; } v; v.u = ((unsigned)u) << 16; return v.f;
}

// ---------------- K0: qT[b][d][j] = bf16(q[b][j][d]); qbf[b][j][d] ----------------
__global__ __launch_bounds__(256) void k0_qprep(const float* __restrict__ q,
        unsigned short* __restrict__ qT, unsigned short* __restrict__ qbf){
    __shared__ float tile[QLN][65];
    const int b  = blockIdx.x;
    const int d0 = blockIdx.y * 64;
    const int t  = threadIdx.x;
    {
        const int col = t & 63, rg = t >> 6;
        #pragma unroll 4
        for (int p = 0; p < 32; ++p){
            int j = p*4 + rg;
            float v = q[(size_t)(b*QLN + j)*DDN + d0 + col];
            tile[j][col] = v;
            qbf[(size_t)(b*QLN + j)*DDN + d0 + col] = (unsigned short)f2bf(v);
        }
    }
    __syncthreads();
    {
        const int j = t & 127, dg = t >> 7;
        #pragma unroll 4
        for (int p = 0; p < 32; ++p){
            int dd = p*2 + dg;
            qT[(size_t)(b*DDN + d0 + dd)*QLN + j] = (unsigned short)f2bf(tile[j][dd]);
        }
    }
}

// ---------------- K0b: s_q[b][j] = q[b][j][:] . w_q ----------------
__global__ __launch_bounds__(256) void k0b_sq(const float* __restrict__ q,
        const float* __restrict__ w_q, float* __restrict__ sq){
    const int b = blockIdx.x;
    const int t = threadIdx.x;
    const int wave = t >> 6, lane = t & 63;
    float wv[8];
    #pragma unroll
    for (int e=0;e<8;++e) wv[e] = w_q[lane*8+e];
    for (int j = wave; j < QLN; j += 4){
        const float* qr = q + (size_t)(b*QLN + j)*DDN + lane*8;
        float s = 0.f;
        #pragma unroll
        for (int e=0;e<8;++e) s += qr[e]*wv[e];
        #pragma unroll
        for (int m=1;m<64;m<<=1) s += __shfl_xor(s, m, 64);
        if (lane==0) sq[b*QLN + j] = s;
    }
}

// ---------------- K0c: q0 = c (exact, nt); cbf = bf16(c*w_cq) into out-q3 slack;
//                       s_c = c . w_c; block 0 also writes inv_wcq ----------------
__global__ __launch_bounds__(256) void k0c_cprep(const float* __restrict__ c,
        const float* __restrict__ w_c, const float* __restrict__ w_cq,
        float* out, float* __restrict__ sc_ws, float* __restrict__ inv_ws){
    const int t = threadIdx.x, lane = t & 63, w = t >> 6;
    const int row0 = blockIdx.x*32 + w*8;
    float4 wc0 = *(const float4*)(w_c  + lane*8);
    float4 wc1 = *(const float4*)(w_c  + lane*8 + 4);
    float4 wq0 = *(const float4*)(w_cq + lane*8);
    float4 wq1 = *(const float4*)(w_cq + lane*8 + 4);
    #pragma unroll 2
    for (int p=0;p<8;++p){
        const size_t gi = (size_t)(row0 + p);
        const float* cr = c + gi*DDN + lane*8;
        f32x4 a  = *(const f32x4*)cr;
        f32x4 bb = *(const f32x4*)(cr+4);
        float s = a.x*wc0.x + a.y*wc0.y + a.z*wc0.z + a.w*wc0.w
                + bb.x*wc1.x + bb.y*wc1.y + bb.z*wc1.z + bb.w*wc1.w;
        #pragma unroll
        for (int m=1;m<64;m<<=1) s += __shfl_xor(s, m, 64);
        float* orow = out + gi*2048;
        __builtin_nontemporal_store(a,  (f32x4*)(orow + lane*8));
        __builtin_nontemporal_store(bb, (f32x4*)(orow + lane*8 + 4));
        uint4 pk;
        pk.x = f2bf(a.x*wq0.x)  | (f2bf(a.y*wq0.y)  << 16);
        pk.y = f2bf(a.z*wq0.z)  | (f2bf(a.w*wq0.w)  << 16);
        pk.z = f2bf(bb.x*wq1.x) | (f2bf(bb.y*wq1.y) << 16);
        pk.w = f2bf(bb.z*wq1.z) | (f2bf(bb.w*wq1.w) << 16);
        *(uint4*)((unsigned short*)(orow + 1792) + lane*8) = pk;   // cbf (cacheable)
        if (lane==0) sc_ws[gi] = s;
    }
    if (blockIdx.x == 0){
        for (int d=t; d<DDN; d+=256){
            float wv = w_cq[d];
            inv_ws[d] = (fabsf(wv) > 1e-35f) ? 1.0f/wv : 0.0f;
        }
    }
}

// staging: one wave fills 4 chunks of 8 rows (128B/row, XOR-swizzled source)
__device__ __forceinline__ void stage_tile(const float* out, size_t girow0, int kc,
        unsigned short* buf, int wm, int lane){
    const int rsub = lane >> 3, c16 = lane & 7;
    #pragma unroll
    for (int r=0;r<4;++r){
        const int chunk = wm*4 + r;
        const int row   = chunk*8 + rsub;
        const int col16 = c16 ^ (row & 7);
        const unsigned short* g =
            (const unsigned short*)(out + (girow0 + row)*2048 + 1792) + kc*64 + col16*8;
        __builtin_amdgcn_global_load_lds((GAS*)g, (LAS*)(buf + chunk*512), 16, 0, 0);
    }
}

// ---------------- K1: GEMM1^T (D[j][i]) -> softmax -> GEMM2^T (D[d][i]) ->
//                  float4 epilogue (q1,q2) + per-tile {M_t,S_t,v_t} ----------------
__global__ __launch_bounds__(256,3) void k1_main(
        float* out, const unsigned short* __restrict__ qbf,
        const unsigned short* __restrict__ qT, const float* __restrict__ sq_ws,
        const float* __restrict__ sc_ws, const float* __restrict__ inv_ws,
        float* __restrict__ vts, float* __restrict__ Mts, float* __restrict__ Sts){
    __shared__ unsigned short sm_u[16384];   // 32KB: staging dbuf (2x16KB) / P^T alias (128x256B)
    __shared__ float sm_vw[4][512];          // 8KB per-wave v_t slabs
    __shared__ float sm_inv[512];            // 2KB
    __shared__ float sm_sq[128], sm_m[128], sm_wrow[128], sm_sc[128];
    __shared__ float sm_red[8];

    const int bid  = blockIdx.x;
    const int swzb = (bid & 7)*64 + (bid >> 3);   // XCD swizzle: batch's tiles share an XCD
    const int b    = swzb >> 3;
    const int tile = swzb & 7;
    const int i0   = tile * 128;
    const int t    = threadIdx.x;
    const int lane = t & 63;
    const int wm   = t >> 6;
    const int l15  = lane & 15;
    const int l4   = lane >> 4;
    const size_t girow0 = (size_t)(b*CLN + i0);

    if (t < 128){ sm_sc[t] = sc_ws[girow0 + t]; sm_sq[t] = sq_ws[b*QLN + t]; }
    sm_inv[t] = inv_ws[t]; sm_inv[t+256] = inv_ws[t+256];

    f32x4 acc[2][8];
    #pragma unroll
    for (int mi=0;mi<2;++mi)
        #pragma unroll
        for (int nj=0;nj<8;++nj) acc[mi][nj] = f32x4{0.f,0.f,0.f,0.f};

    // ---- GEMM1: D[j][i] = sum_d qbf[j][d] * cbf[i][d] ----
    stage_tile(out, girow0, 0, sm_u, wm, lane);
    __syncthreads();
    const unsigned short* qbbase = qbf + (size_t)b*QLN*DDN;
    for (int kc=0; kc<8; ++kc){
        const int cur = kc & 1;
        if (kc < 7) stage_tile(out, girow0, kc+1, sm_u + (cur^1)*8192, wm, lane);
        const char* abase = (const char*)sm_u + cur*16384;
        #pragma unroll
        for (int ks=0; ks<2; ++ks){
            bf16x8 af[2], bfr[8];
            #pragma unroll
            for (int mi=0;mi<2;++mi){
                const int row = wm*32 + mi*16 + l15;
                af[mi] = *(const bf16x8*)(abase + row*128 + ((ks*64 + l4*16) ^ ((row&7)<<4)));
            }
            #pragma unroll
            for (int nj=0;nj<8;++nj)
                bfr[nj] = *(const bf16x8*)(qbbase + (size_t)(nj*16+l15)*DDN + kc*64 + ks*32 + l4*8);
            #pragma unroll
            for (int mi=0;mi<2;++mi)
                #pragma unroll
                for (int nj=0;nj<8;++nj)
                    acc[mi][nj] = __builtin_amdgcn_mfma_f32_16x16x32_bf16(bfr[nj], af[mi], acc[mi][nj], 0,0,0);
        }
        __syncthreads();
    }

    // ---- row softmax: lane owns row i = wm*32+mi*16+l15; j = nj*16 + l4*4 + r ----
    f32x4 sq4[8];
    #pragma unroll
    for (int nj=0;nj<8;++nj) sq4[nj] = *(const f32x4*)(sm_sq + nj*16 + l4*4);

    #pragma unroll
    for (int mi=0;mi<2;++mi){
        const int irow = wm*32 + mi*16 + l15;
        float rmax = -1e30f;
        #pragma unroll
        for (int nj=0;nj<8;++nj){
            #pragma unroll
            for (int r=0;r<4;++r){
                float v = acc[mi][nj][r] + sq4[nj][r];
                acc[mi][nj][r] = v;
                rmax = fmaxf(rmax, v);
            }
        }
        rmax = fmaxf(rmax, __shfl_xor(rmax, 16, 64));
        rmax = fmaxf(rmax, __shfl_xor(rmax, 32, 64));
        if (l4 == 0) sm_m[irow] = sm_sc[irow] + rmax;
        float rsum = 0.f;
        #pragma unroll
        for (int nj=0;nj<8;++nj){
            #pragma unroll
            for (int r=0;r<4;++r){
                float pv = __expf(acc[mi][nj][r] - rmax);
                acc[mi][nj][r] = pv;
                rsum += pv;
            }
        }
        rsum += __shfl_xor(rsum, 16, 64);
        rsum += __shfl_xor(rsum, 32, 64);
        const float pinv = 1.f / rsum;
        #pragma unroll
        for (int nj=0;nj<8;++nj){
            uint2 u;
            u.x = f2bf(acc[mi][nj][0]*pinv) | (f2bf(acc[mi][nj][1]*pinv) << 16);
            u.y = f2bf(acc[mi][nj][2]*pinv) | (f2bf(acc[mi][nj][3]*pinv) << 16);
            *(uint2*)((char*)sm_u + irow*256 + ((nj*32 + l4*8) ^ ((irow&7)<<4))) = u;
        }
    }
    __syncthreads();   // P^T + sm_m visible

    // ---- tile max/sum for b_att + per-row weights ----
    float v0 = (t < 128) ? sm_m[t] : -1e30f;
    #pragma unroll
    for (int m=1;m<64;m<<=1) v0 = fmaxf(v0, __shfl_xor(v0, m, 64));
    if (lane==0) sm_red[wm] = v0;
    __syncthreads();
    const float mt = fmaxf(sm_red[0], sm_red[1]);
    float ev = (t < 128) ? __expf(sm_m[t] - mt) : 0.f;
    if (t < 128) sm_wrow[t] = ev;
    float es = ev;
    #pragma unroll
    for (int m=1;m<64;m<<=1) es += __shfl_xor(es, m, 64);
    if (lane==0) sm_red[4+wm] = es;
    __syncthreads();
    const float St = sm_red[4]+sm_red[5]+sm_red[6]+sm_red[7];
    float wrow_reg[2];
    wrow_reg[0] = sm_wrow[wm*32 + l15];
    wrow_reg[1] = sm_wrow[wm*32 + 16 + l15];

    // ---- GEMM2: D[d][i] = sum_j qT[d][j] * P^T[i][j]; float4 epilogue ----
    const unsigned short* qtbase = qT + (size_t)b*DDN*QLN;
    for (int dc=0; dc<4; ++dc){
        f32x4 acc2[8][2];
        #pragma unroll
        for (int dt=0;dt<8;++dt){ acc2[dt][0] = f32x4{0,0,0,0}; acc2[dt][1] = f32x4{0,0,0,0}; }
        #pragma unroll
        for (int jc=0; jc<4; ++jc){
            bf16x8 b2[2];
            #pragma unroll
            for (int mi=0;mi<2;++mi){
                const int irow = wm*32 + mi*16 + l15;
                b2[mi] = *(const bf16x8*)((char*)sm_u + irow*256 + ((jc*64 + l4*16) ^ ((irow&7)<<4)));
            }
            #pragma unroll
            for (int dt=0;dt<8;++dt){
                bf16x8 a2 = *(const bf16x8*)(qtbase + (size_t)(dc*128 + dt*16 + l15)*QLN + jc*32 + l4*8);
                acc2[dt][0] = __builtin_amdgcn_mfma_f32_16x16x32_bf16(a2, b2[0], acc2[dt][0], 0,0,0);
                acc2[dt][1] = __builtin_amdgcn_mfma_f32_16x16x32_bf16(a2, b2[1], acc2[dt][1], 0,0,0);
            }
        }
        #pragma unroll
        for (int dt=0; dt<8; ++dt){
            const int d0 = dc*128 + dt*16 + l4*4;
            f32x4 iv = *(const f32x4*)(sm_inv + d0);
            f32x4 vp = f32x4{0,0,0,0};
            #pragma unroll
            for (int mi=0; mi<2; ++mi){
                const int irow = wm*32 + mi*16 + l15;
                const size_t gi = girow0 + irow;
                const unsigned short* cb = (const unsigned short*)(out + gi*2048 + 1792) + d0;
                uint2 u = *(const uint2*)cb;   // 4 bf16, L2-hot (just staged)
                f32x4 cv;
                cv.x = bf2f((unsigned short)(u.x & 0xffff)) * iv.x;
                cv.y = bf2f((unsigned short)(u.x >> 16))    * iv.y;
                cv.z = bf2f((unsigned short)(u.y & 0xffff)) * iv.z;
                cv.w = bf2f((unsigned short)(u.y >> 16))    * iv.w;
                f32x4 v = acc2[dt][mi];
                float* orow = out + gi*2048;
                __builtin_nontemporal_store(v,  (f32x4*)(orow + 512 + d0));     // q1 = c2q
                f32x4 cq; cq.x=cv.x*v.x; cq.y=cv.y*v.y; cq.z=cv.z*v.z; cq.w=cv.w*v.w;
                __builtin_nontemporal_store(cq, (f32x4*)(orow + 1024 + d0));    // q2 = c*c2q
                const float w = wrow_reg[mi];
                vp.x += w*cv.x; vp.y += w*cv.y; vp.z += w*cv.z; vp.w += w*cv.w;
            }
            #pragma unroll
            for (int m=1;m<16;m<<=1){
                vp.x += __shfl_xor(vp.x, m, 64); vp.y += __shfl_xor(vp.y, m, 64);
                vp.z += __shfl_xor(vp.z, m, 64); vp.w += __shfl_xor(vp.w, m, 64);
            }
            if (l15 == 0) *(f32x4*)(&sm_vw[wm][d0]) = vp;
        }
    }
    __syncthreads();
    for (int d=t; d<DDN; d+=256){
        float s = sm_vw[0][d] + sm_vw[1][d] + sm_vw[2][d] + sm_vw[3][d];
        vts[(size_t)(b*8 + tile)*DDN + d] = s;
    }
    if (t == 0){ Mts[b*8 + tile] = mt; Sts[b*8 + tile] = St; }
}

// ---------------- K2: combine 8 tiles -> q2c[b][d] ----------------
__global__ __launch_bounds__(256) void k2_combine(const float* __restrict__ vts,
        const float* __restrict__ Mts, const float* __restrict__ Sts,
        float* __restrict__ q2c){
    const int b = blockIdx.x, t = threadIdx.x;
    float Mt[8]; float M = -1e30f;
    #pragma unroll
    for (int i=0;i<8;++i){ Mt[i] = Mts[b*8+i]; M = fmaxf(M, Mt[i]); }
    float coef[8]; float denom = 0.f;
    #pragma unroll
    for (int i=0;i<8;++i){ coef[i] = __expf(Mt[i]-M); denom += coef[i]*Sts[b*8+i]; }
    const float inv = 1.f/denom;
    for (int d=t; d<DDN; d+=256){
        float s = 0.f;
        #pragma unroll
        for (int i=0;i<8;++i) s += coef[i]*vts[(size_t)(b*8+i)*DDN + d];
        q2c[b*DDN + d] = s*inv;
    }
}

// ---------------- K3: q3 = c * q2c (c reconstructed from cbf in q3 slack) ----------------
__global__ __launch_bounds__(256) void k3_cq2c(float* out,
        const float* __restrict__ q2c, const float* __restrict__ inv_ws){
    const int t = threadIdx.x;
    const int rloc = t >> 6, ch = t & 63;
    for (int pass=0; pass<8; ++pass){
        const size_t rb = (size_t)blockIdx.x + (size_t)pass*2048;
        const size_t gi = rb*4 + rloc;
        const int b = (int)(gi >> 10);
        const unsigned short* cb = (const unsigned short*)(out + gi*2048 + 1792) + ch*8;
        uint4 raw = *(const uint4*)cb;
        const float* qp = q2c + b*DDN + ch*8;
        float4 qa = *(const float4*)qp;
        float4 qb = *(const float4*)(qp+4);
        const float* ip = inv_ws + ch*8;
        float4 ia = *(const float4*)ip;
        float4 ib = *(const float4*)(ip+4);
        f32x4 o0, o1;
        o0.x = bf2f((unsigned short)(raw.x & 0xffff)) * ia.x * qa.x;
        o0.y = bf2f((unsigned short)(raw.x >> 16))    * ia.y * qa.y;
        o0.z = bf2f((unsigned short)(raw.y & 0xffff)) * ia.z * qa.z;
        o0.w = bf2f((unsigned short)(raw.y >> 16))    * ia.w * qa.w;
        o1.x = bf2f((unsigned short)(raw.z & 0xffff)) * ib.x * qb.x;
        o1.y = bf2f((unsigned short)(raw.z >> 16))    * ib.y * qb.y;
        o1.z = bf2f((unsigned short)(raw.w & 0xffff)) * ib.z * qb.z;
        o1.w = bf2f((unsigned short)(raw.w >> 16))    * ib.w * qb.w;
        __syncthreads();   // all 4 rows' cbf read before any q3 overwrite
        f32x4* wp = (f32x4*)(out + gi*2048 + 1536) + ch*2;
        __builtin_nontemporal_store(o0, wp);
        __builtin_nontemporal_store(o1, wp+1);
    }
}

extern "C" void kernel_launch(void* const* d_in, const int* in_sizes, int n_in,
                              void* d_out, int out_size, void* d_ws, size_t ws_size,
                              hipStream_t stream) {
    const float* c    = (const float*)d_in[0];
    const float* q    = (const float*)d_in[1];
    const float* w_c  = (const float*)d_in[2];
    const float* w_q  = (const float*)d_in[4];
    const float* w_cq = (const float*)d_in[6];
    float* out = (float*)d_out;

    char* ws = (char*)d_ws;
    unsigned short* qT  = (unsigned short*)ws;                     // 8 MiB
    unsigned short* qbf = (unsigned short*)(ws + 8388608);         // 8 MiB
    float* sq  = (float*)(ws + 16777216);                          // 32 KB
    float* sc  = (float*)(ws + 16777216 + 32768);                  // 256 KB
    float* inv = (float*)(ws + 16777216 + 32768 + 262144);         // 2 KB
    float* Mts = (float*)(ws + 16777216 + 32768 + 262144 + 2048);  // 2 KB
    float* Sts = (float*)(ws + 16777216 + 32768 + 262144 + 4096);  // 2 KB
    float* vts = (float*)(ws + 16777216 + 32768 + 262144 + 6144);  // 1 MiB
    float* q2c = (float*)(ws + 16777216 + 32768 + 262144 + 6144 + 1048576); // 128 KB

    k0_qprep<<<dim3(NB, 8), 256, 0, stream>>>(q, qT, qbf);
    k0b_sq<<<NB, 256, 0, stream>>>(q, w_q, sq);
    k0c_cprep<<<2048, 256, 0, stream>>>(c, w_c, w_cq, out, sc, inv);
    k1_main<<<NB*8, 256, 0, stream>>>(out, qbf, qT, sq, sc, inv, vts, Mts, Sts);
    k2_combine<<<NB, 256, 0, stream>>>(vts, Mts, Sts, q2c);
    k3_cq2c<<<2048, 256, 0, stream>>>(out, q2c, inv);
}